// Round 19
// baseline (123.749 us; speedup 1.0000x reference)
//
#include <hip/hip_runtime.h>
#include <hip/hip_bf16.h>

#define HDIM 1024
#define SEQ 2048
#define BATCH 16
#define M_TOT (SEQ*BATCH)   // 32768
#define NBLK 4              // N split into 4 chunks of 256
#define BM 256
#define BN 256
#define BKT 64              // K-tile depth
#define NT (HDIM/BKT)       // 16 K-tiles

// prep_all grid layout
#define NB_ENC ((M_TOT*HDIM)/(8*256))   // 16384 (worst case: all rows kept)
#define NB_WE  ((HDIM*HDIM)/(8*256))    // 512
#define NB_QK  (HDIM)                   // 1024

typedef __attribute__((ext_vector_type(8))) short short8;
typedef __attribute__((ext_vector_type(4))) float f32x4;

typedef const void __attribute__((address_space(1))) gvoid_t;
typedef void __attribute__((address_space(3))) svoid_t;
#define GLD16(gp, lp) __builtin_amdgcn_global_load_lds((gvoid_t*)(gp), (svoid_t*)(lp), 16, 0, 0)
#define VMC(N) asm volatile("s_waitcnt vmcnt(" #N ")" ::: "memory")

static __device__ __forceinline__ unsigned short f2bf(float f) {
    unsigned int x = __float_as_uint(f);
    unsigned int r = (x + 0x7FFFu + ((x >> 16) & 1u)) >> 16;  // RNE
    return (unsigned short)r;
}

// ---------------- kernel 0: mask compaction in MASK-LINEAR order (single block) ----------------
// l = b*SEQ + s (mask's native layout). keep iff mask[l]==0. j-order = ascending l (batch-major;
// any consistent permutation is valid). rowidx[j] = m = s*16+b = ((l&2047)<<4)|(l>>11); jof[m]=j.
__global__ __launch_bounds__(1024) void scan_kernel(const int* __restrict__ mask,
                                                    int* __restrict__ rowidx,
                                                    int* __restrict__ jof,
                                                    int* __restrict__ nkeep) {
    int t = threadIdx.x;              // 0..1023, 32 consecutive ints each (vectorized int4 x8)
    int base = t * 32;
    unsigned flags = 0;
    int cnt = 0;
    const int4* m4 = reinterpret_cast<const int4*>(mask + base);
#pragma unroll
    for (int v = 0; v < 8; ++v) {
        int4 x = m4[v];
        if (x.x == 0) { flags |= 1u << (v * 4 + 0); cnt++; }
        if (x.y == 0) { flags |= 1u << (v * 4 + 1); cnt++; }
        if (x.z == 0) { flags |= 1u << (v * 4 + 2); cnt++; }
        if (x.w == 0) { flags |= 1u << (v * 4 + 3); cnt++; }
    }
    // inclusive scan of cnt within wave (64 lanes)
    int lane = t & 63, wv = t >> 6;
    int inc = cnt;
    for (int off = 1; off < 64; off <<= 1) {
        int o = __shfl_up(inc, off);
        if (lane >= off) inc += o;
    }
    __shared__ int wsum[16], wbase[16];
    if (lane == 63) wsum[wv] = inc;
    __syncthreads();
    if (t == 0) {
        int acc = 0;
        for (int w = 0; w < 16; ++w) { wbase[w] = acc; acc += wsum[w]; }
        nkeep[0] = acc;
    }
    __syncthreads();
    int e = wbase[wv] + inc - cnt;    // exclusive prefix for this thread
#pragma unroll
    for (int i = 0; i < 32; ++i) {
        if ((flags >> i) & 1u) {
            int l = base + i;
            int m = ((l & 2047) << 4) | (l >> 11);   // m = s*16 + b
            rowidx[e] = m;
            jof[m] = e;
            e++;
        }
    }
}

// ---------------- kernel 1: fused prep = compact-conv_enc + conv_we + qk ----------------
__global__ __launch_bounds__(256) void prep_all(const float* __restrict__ hidden,
                                                const float* __restrict__ enc,
                                                const float* __restrict__ attn_w,
                                                const float* __restrict__ attn_b,
                                                const int* __restrict__ rowidx,
                                                const int* __restrict__ nkp,
                                                float* __restrict__ q,
                                                __hip_bfloat16* __restrict__ web,
                                                __hip_bfloat16* __restrict__ encb) {
    int bid = blockIdx.x;
    if (bid < NB_ENC) {
        // compacted enc fp32 -> bf16: row j of encb = enc row rowidx[j]; pad rows zeroed
        int nkeep = nkp[0];
        int npad = (nkeep + 255) & ~255;
        int j = bid * 2 + (threadIdx.x >> 7);      // 2 rows per block, 128 threads each
        if (j >= npad) return;
        int col = (threadIdx.x & 127) * 8;
        unsigned short* dst = (unsigned short*)encb + (size_t)j * HDIM + col;
        if (j >= nkeep) {
            short8 z = (short8)0;
            *reinterpret_cast<short8*>(dst) = z;
            return;
        }
        int m = rowidx[j];
        const float4* s4 = reinterpret_cast<const float4*>(enc + (size_t)m * HDIM + col);
        float4 a = s4[0], b = s4[1];
        union { unsigned short u[8]; short8 v; } cv;
        cv.u[0] = f2bf(a.x); cv.u[1] = f2bf(a.y); cv.u[2] = f2bf(a.z); cv.u[3] = f2bf(a.w);
        cv.u[4] = f2bf(b.x); cv.u[5] = f2bf(b.y); cv.u[6] = f2bf(b.z); cv.u[7] = f2bf(b.w);
        *reinterpret_cast<short8*>(dst) = cv.v;
        return;
    }
    if (bid < NB_ENC + NB_WE) {
        size_t i0 = ((size_t)(bid - NB_ENC) * 256 + threadIdx.x) * 8;
        int n = (int)(i0 >> 10);
        int h = (int)(i0 & 1023);
        const float4* src = reinterpret_cast<const float4*>(attn_w + (size_t)n * (2 * HDIM) + HDIM + h);
        float4 a = src[0], b = src[1];
        union { unsigned short u[8]; short8 v; } cv;
        cv.u[0] = f2bf(a.x); cv.u[1] = f2bf(a.y); cv.u[2] = f2bf(a.z); cv.u[3] = f2bf(a.w);
        cv.u[4] = f2bf(b.x); cv.u[5] = f2bf(b.y); cv.u[6] = f2bf(b.z); cv.u[7] = f2bf(b.w);
        *reinterpret_cast<short8*>((unsigned short*)web + i0) = cv.v;
        return;
    }
    int k = bid - (NB_ENC + NB_WE);   // 0..1023
    int tid = threadIdx.x;
    const float* w = attn_w + (size_t)k * (2 * HDIM);
    float p[BATCH];
#pragma unroll
    for (int b = 0; b < BATCH; b++) p[b] = 0.f;
    for (int h = tid; h < HDIM; h += 256) {
        float wv = w[h];
#pragma unroll
        for (int b = 0; b < BATCH; b++) p[b] += hidden[b * HDIM + h] * wv;
    }
#pragma unroll
    for (int b = 0; b < BATCH; b++) {
        for (int off = 32; off; off >>= 1) p[b] += __shfl_down(p[b], off);
    }
    __shared__ float red[4][BATCH];
    int lane = tid & 63, wid = tid >> 6;
    if (lane == 0) {
#pragma unroll
        for (int b = 0; b < BATCH; b++) red[wid][b] = p[b];
    }
    __syncthreads();
    if (tid < BATCH) {
        float s = red[0][tid] + red[1][tid] + red[2][tid] + red[3][tid] + attn_b[k];
        q[(size_t)tid * HDIM + k] = s;
    }
}

// ---------------- kernel 2: 256x256 GEMM over COMPACTED M, 1 barrier/tile ----------------
// K-loop identical to verified R15; epilogue uses per-row batch table rowb[row]=rowidx[j]&15.
// Block decode: XCD = bm&7 (uniform activity under early-exit), same-bm quartet co-XCD.
__global__ __launch_bounds__(512, 2) void gemm8(const __hip_bfloat16* __restrict__ encb,
                                                const __hip_bfloat16* __restrict__ web,
                                                const float* __restrict__ qv,
                                                const float* __restrict__ score_w,
                                                const int* __restrict__ rowidx,
                                                const int* __restrict__ nkp,
                                                float* __restrict__ part) {
    __shared__ __align__(16) char pool[163840];

    int tid = threadIdx.x;
    int lane = tid & 63;
    int wid = tid >> 6;        // 0..7
    int wr = wid >> 2;         // 0..1  M half
    int wc = wid & 3;          // 0..3  N quarter

    // XCD-uniform decode: bid = (bm&7) + 8*((bm>>3)*4 + bn)  ->  XCD(bid%8) = bm&7.
    int bid = blockIdx.x;
    int bm = ((bid >> 5) << 3) | (bid & 7);   // 0..127
    int bn = (bid >> 3) & 3;                  // 0..3
    int m0 = bm * BM, n0 = bn * BN;

    int nkeep = nkp[0];
    int npad = (nkeep + 255) & ~255;
    if (m0 >= npad) return;    // uniform early exit: this M-tile is entirely masked out

    // ---- staging thread constants (pre-swizzled global source) ----
    int srow = tid >> 3;                                   // 0..63
    int scolb = (((tid & 7) ^ ((tid >> 3) & 7)) << 4);     // swizzled byte col 0..127
    const char* eb = (const char*)encb;
    const char* wb = (const char*)web;

    auto STG = [&](const char* g, int ldsoff) {
        GLD16(g + (size_t)srow * 2048 + scolb, pool + ldsoff + wid * 1024);
        GLD16(g + (size_t)(srow + 64) * 2048 + scolb, pool + ldsoff + 8192 + wid * 1024);
    };
    auto APTR = [&](int kt, int h) { return eb + ((size_t)(m0 + h * 128) * HDIM + kt * BKT) * 2; };
    auto BPTR = [&](int kt, int h) { return wb + ((size_t)(n0 + h * 128) * HDIM + kt * BKT) * 2; };
#define ALDS(par, h) ((par) * 32768 + (h) * 16384)
#define BLDS(buf, h) (65536 + (buf) * 32768 + (h) * 16384)

    // ---- fragment-read constants (swizzled ds_read addresses) ----
    int lq = lane & 15, lh = lane >> 4;
    int flip = (lane & 7) << 4;
    int pks0 = lq * 128 + ((lh * 16) ^ flip);
    int pks1 = lq * 128 + (((64 + lh * 16)) ^ flip);
    int aFB = wr * 16384;                                   // + par*32768
    int bOFF = (wc >> 1) * 16384 + (wc & 1) * 8192;         // within B buffer

    f32x4 acc[8][4];
#pragma unroll
    for (int i = 0; i < 8; i++)
#pragma unroll
        for (int j = 0; j < 4; j++) acc[i][j] = (f32x4)0.f;
    short8 br[4][2];

#define RD8(off) (*reinterpret_cast<const short8*>(pool + (off)))

#define CLUSTER(Q, PAR, BB, STAGE_STMT)                                                   \
    {                                                                                     \
        if ((Q) == 0) {                                                                   \
            _Pragma("unroll") for (int nj = 0; nj < 4; ++nj) {                            \
                br[nj][0] = RD8(65536 + (BB) * 32768 + bOFF + nj * 2048 + pks0);          \
                br[nj][1] = RD8(65536 + (BB) * 32768 + bOFF + nj * 2048 + pks1);          \
            }                                                                             \
        }                                                                                 \
        short8 a0k0 = RD8(aFB + (PAR) * 32768 + (2 * (Q)) * 2048 + pks0);                 \
        short8 a0k1 = RD8(aFB + (PAR) * 32768 + (2 * (Q)) * 2048 + pks1);                 \
        short8 a1k0 = RD8(aFB + (PAR) * 32768 + (2 * (Q) + 1) * 2048 + pks0);             \
        short8 a1k1 = RD8(aFB + (PAR) * 32768 + (2 * (Q) + 1) * 2048 + pks1);             \
        STAGE_STMT;                                                                       \
        __builtin_amdgcn_s_setprio(1);                                                    \
        _Pragma("unroll") for (int nj = 0; nj < 4; ++nj) {                                \
            acc[2 * (Q)][nj] = __builtin_amdgcn_mfma_f32_16x16x32_bf16(a0k0, br[nj][0], acc[2 * (Q)][nj], 0, 0, 0); \
            acc[2 * (Q)][nj] = __builtin_amdgcn_mfma_f32_16x16x32_bf16(a0k1, br[nj][1], acc[2 * (Q)][nj], 0, 0, 0); \
            acc[2 * (Q) + 1][nj] = __builtin_amdgcn_mfma_f32_16x16x32_bf16(a1k0, br[nj][0], acc[2 * (Q) + 1][nj], 0, 0, 0); \
            acc[2 * (Q) + 1][nj] = __builtin_amdgcn_mfma_f32_16x16x32_bf16(a1k1, br[nj][1], acc[2 * (Q) + 1][nj], 0, 0, 0); \
        }                                                                                 \
        __builtin_amdgcn_s_setprio(0);                                                    \
    }

#define TILE(PAR, BB, S1, S2, S3, S4, CLOSE)                                              \
    {                                                                                     \
        CLUSTER(0, PAR, BB, S1);                                                          \
        CLUSTER(1, PAR, BB, S2);                                                          \
        CLUSTER(2, PAR, BB, S3);                                                          \
        CLUSTER(3, PAR, BB, S4);                                                          \
        CLOSE;                                                                            \
        __builtin_amdgcn_s_barrier();                                                     \
        __builtin_amdgcn_sched_barrier(0);                                                \
    }

    // ---- prologue: stage A(0), B(0), B(1); land A(0)+B(0), keep B(1) in flight ----
    STG(APTR(0, 0), ALDS(0, 0));
    STG(APTR(0, 1), ALDS(0, 1));
    STG(BPTR(0, 0), BLDS(0, 0));
    STG(BPTR(0, 1), BLDS(0, 1));
    STG(BPTR(1, 0), BLDS(1, 0));
    STG(BPTR(1, 1), BLDS(1, 1));
    VMC(4);
    __builtin_amdgcn_s_barrier();
    __builtin_amdgcn_sched_barrier(0);

    // ---- main loop: 2 x 6 tiles (pattern period lcm(2,3)=6), then 4 peeled ----
#pragma unroll 1
    for (int J = 0; J < 2; ++J) {
        int t = 6 * J;
        TILE(0, 0, STG(APTR(t + 1, 0), ALDS(1, 0)), STG(APTR(t + 1, 1), ALDS(1, 1)),
                   STG(BPTR(t + 2, 0), BLDS(2, 0)), STG(BPTR(t + 2, 1), BLDS(2, 1)), VMC(4));
        TILE(1, 1, STG(APTR(t + 2, 0), ALDS(0, 0)), STG(APTR(t + 2, 1), ALDS(0, 1)),
                   STG(BPTR(t + 3, 0), BLDS(0, 0)), STG(BPTR(t + 3, 1), BLDS(0, 1)), VMC(4));
        TILE(0, 2, STG(APTR(t + 3, 0), ALDS(1, 0)), STG(APTR(t + 3, 1), ALDS(1, 1)),
                   STG(BPTR(t + 4, 0), BLDS(1, 0)), STG(BPTR(t + 4, 1), BLDS(1, 1)), VMC(4));
        TILE(1, 0, STG(APTR(t + 4, 0), ALDS(0, 0)), STG(APTR(t + 4, 1), ALDS(0, 1)),
                   STG(BPTR(t + 5, 0), BLDS(2, 0)), STG(BPTR(t + 5, 1), BLDS(2, 1)), VMC(4));
        TILE(0, 1, STG(APTR(t + 5, 0), ALDS(1, 0)), STG(APTR(t + 5, 1), ALDS(1, 1)),
                   STG(BPTR(t + 6, 0), BLDS(0, 0)), STG(BPTR(t + 6, 1), BLDS(0, 1)), VMC(4));
        TILE(1, 2, STG(APTR(t + 6, 0), ALDS(0, 0)), STG(APTR(t + 6, 1), ALDS(0, 1)),
                   STG(BPTR(t + 7, 0), BLDS(1, 0)), STG(BPTR(t + 7, 1), BLDS(1, 1)), VMC(4));
    }
    // tiles 12..15
    TILE(0, 0, STG(APTR(13, 0), ALDS(1, 0)), STG(APTR(13, 1), ALDS(1, 1)),
               STG(BPTR(14, 0), BLDS(2, 0)), STG(BPTR(14, 1), BLDS(2, 1)), VMC(4));
    TILE(1, 1, STG(APTR(14, 0), ALDS(0, 0)), STG(APTR(14, 1), ALDS(0, 1)),
               STG(BPTR(15, 0), BLDS(0, 0)), STG(BPTR(15, 1), BLDS(0, 1)), VMC(4));
    TILE(0, 2, STG(APTR(15, 0), ALDS(1, 0)), STG(APTR(15, 1), ALDS(1, 1)), , , VMC(0));
    TILE(1, 0, , , , , );

    // ---- fused epilogue: LDS transpose-reduce with per-row batch table ----
    float* q_lds = reinterpret_cast<float*>(pool);            // [16][256] 16KB
    float* sc_lds = reinterpret_cast<float*>(pool + 16384);   // [256] 1KB
    int* rowb = reinterpret_cast<int*>(pool + 17408);         // [256] 1KB: batch of each row
    float* red = reinterpret_cast<float*>(pool + 18432);      // [4][256][20] f32 = 80KB
    {
        int qb = tid >> 5;            // 0..15
        int kl = (tid & 31) * 8;      // 0..248
        const float4* src = reinterpret_cast<const float4*>(qv + (size_t)qb * HDIM + n0 + kl);
        float4 v0 = src[0], v1 = src[1];
        *reinterpret_cast<float4*>(&q_lds[qb * 256 + kl]) = v0;
        *reinterpret_cast<float4*>(&q_lds[qb * 256 + kl + 4]) = v1;
        if (tid < BN) sc_lds[tid] = score_w[n0 + tid];
        if (tid < BM) rowb[tid] = (m0 + tid < nkeep) ? (rowidx[m0 + tid] & 15) : 0;
    }
    __syncthreads();

#pragma unroll
    for (int mi = 0; mi < 8; ++mi) {
#pragma unroll
        for (int r = 0; r < 4; ++r) {
            int row = wr * 128 + mi * 16 + lh * 4 + r;
            int bq = rowb[row];       // true batch of this compacted row (broadcast read)
            float s = 0.f;
#pragma unroll
            for (int nj = 0; nj < 4; ++nj) {
                int kl = wc * 64 + nj * 16 + lq;
                float v = acc[mi][nj][r] + q_lds[bq * 256 + kl];
                float t = 1.f - 2.f / (__expf(2.f * v) + 1.f);  // tanh(v)
                s += sc_lds[kl] * t;
            }
            red[(wc * 256 + row) * 20 + lq] = s;
        }
    }
    __syncthreads();
    if (tid < BM) {
        float t = 0.f;
#pragma unroll
        for (int w4 = 0; w4 < 4; ++w4) {
            const f32x4* p = reinterpret_cast<const f32x4*>(&red[(w4 * 256 + tid) * 20]);
#pragma unroll
            for (int i = 0; i < 4; ++i) {
                f32x4 v = p[i];
                t += v[0] + v[1] + v[2] + v[3];
            }
        }
        part[(size_t)bn * M_TOT + m0 + tid] = t;
    }
#undef CLUSTER
#undef TILE
#undef RD8
#undef ALDS
#undef BLDS
}

// ---------------- kernel 3: gather partials via jof + mask + softmax over S ----------------
__global__ __launch_bounds__(256) void softmax_kernel(const float* __restrict__ part,
                                                      const int* __restrict__ mask,
                                                      const int* __restrict__ jof,
                                                      float* __restrict__ out) {
    int b = blockIdx.x;
    int tid = threadIdx.x;
    __shared__ float e_lds[SEQ];
    __shared__ float red[4], red2[4];
    int lane = tid & 63, wid = tid >> 6;
    float lmax = -3.4e38f;
    for (int it = 0; it < SEQ / 256; ++it) {
        int s = it * 256 + tid;
        float e = -1e12f;
        if (!mask[(size_t)b * SEQ + s]) {
            int m = s * BATCH + b;
            int j = jof[m];
            float acc = 0.f;
#pragma unroll
            for (int c = 0; c < NBLK; c++) acc += part[(size_t)c * M_TOT + j];
            e = acc;
        }
        e_lds[s] = e;
        lmax = fmaxf(lmax, e);
    }
    for (int off = 32; off; off >>= 1) lmax = fmaxf(lmax, __shfl_xor(lmax, off));
    if (lane == 0) red[wid] = lmax;
    __syncthreads();
    float gmax = fmaxf(fmaxf(red[0], red[1]), fmaxf(red[2], red[3]));
    float lsum = 0.f;
    for (int it = 0; it < SEQ / 256; ++it) {
        int s = it * 256 + tid;
        float p = __expf(e_lds[s] - gmax);
        e_lds[s] = p;
        lsum += p;
    }
    for (int off = 32; off; off >>= 1) lsum += __shfl_xor(lsum, off);
    if (lane == 0) red2[wid] = lsum;
    __syncthreads();
    float inv = 1.f / (red2[0] + red2[1] + red2[2] + red2[3]);
    for (int it = 0; it < SEQ / 256; ++it) {
        int s = it * 256 + tid;
        out[(size_t)b * SEQ + s] = e_lds[s] * inv;
    }
}

extern "C" void kernel_launch(void* const* d_in, const int* in_sizes, int n_in,
                              void* d_out, int out_size, void* d_ws, size_t ws_size,
                              hipStream_t stream) {
    const float* hidden   = (const float*)d_in[0];
    const float* enc      = (const float*)d_in[1];
    const int*   seq_mask = (const int*)d_in[2];
    const float* attn_w   = (const float*)d_in[3];
    const float* attn_b   = (const float*)d_in[4];
    const float* score_w  = (const float*)d_in[5];
    float* out = (float*)d_out;

    char* ws = (char*)d_ws;
    float* q = (float*)ws;                                            // 64 KB   @ 0
    __hip_bfloat16* web = (__hip_bfloat16*)(ws + 65536);              // 2 MB    @ 64K
    float* part = (float*)(ws + 65536 + 2 * 1024 * 1024);             // 512 KB  @ 64K+2M
    int* rowidx = (int*)(ws + 65536 + 2 * 1024 * 1024 + 512 * 1024);  // 128 KB
    int* jof    = (int*)(ws + 65536 + 2 * 1024 * 1024 + 640 * 1024);  // 128 KB
    int* nkeep  = (int*)(ws + 65536 + 2 * 1024 * 1024 + 768 * 1024);  // 4 B
    __hip_bfloat16* encb = (__hip_bfloat16*)(ws + 65536 + 3 * 1024 * 1024);  // 64 MB

    scan_kernel<<<dim3(1), dim3(1024), 0, stream>>>(seq_mask, rowidx, jof, nkeep);
    prep_all<<<dim3(NB_ENC + NB_WE + NB_QK), dim3(256), 0, stream>>>(hidden, enc, attn_w, attn_b,
                                                                     rowidx, nkeep, q, web, encb);
    gemm8<<<dim3(NBLK * (M_TOT / BM)), dim3(512), 0, stream>>>(encb, web, q, score_w,
                                                               rowidx, nkeep, part);
    softmax_kernel<<<dim3(BATCH), dim3(256), 0, stream>>>(part, seq_mask, jof, out);
}

// Round 20
// 123.150 us; speedup vs baseline: 1.0049x; 1.0049x over previous
//
#include <hip/hip_runtime.h>
#include <hip/hip_bf16.h>

#define HDIM 1024
#define SEQ 2048
#define BATCH 16
#define M_TOT (SEQ*BATCH)   // 32768
#define NBLK 4              // N split into 4 chunks of 256
#define BM 256
#define BN 256
#define BKT 64              // K-tile depth
#define NT (HDIM/BKT)       // 16 K-tiles
#define MMAIN 16384         // rows handled by the main 256-tile gemm (64 M-tiles)

// prep_all grid layout
#define NB_ENC ((M_TOT*HDIM)/(8*256))   // 16384 (covers all 32768 rows, 2/block)
#define NB_WE  ((HDIM*HDIM)/(8*256))    // 512
#define NB_QK  (HDIM)                   // 1024

typedef __attribute__((ext_vector_type(8))) short short8;
typedef __attribute__((ext_vector_type(4))) float f32x4;

typedef const void __attribute__((address_space(1))) gvoid_t;
typedef void __attribute__((address_space(3))) svoid_t;
#define GLD16(gp, lp) __builtin_amdgcn_global_load_lds((gvoid_t*)(gp), (svoid_t*)(lp), 16, 0, 0)
#define VMC(N) asm volatile("s_waitcnt vmcnt(" #N ")" ::: "memory")

static __device__ __forceinline__ unsigned short f2bf(float f) {
    unsigned int x = __float_as_uint(f);
    unsigned int r = (x + 0x7FFFu + ((x >> 16) & 1u)) >> 16;  // RNE
    return (unsigned short)r;
}

// ---------------- kernel 0: mask compaction in MASK-LINEAR order (single block) ----------------
__global__ __launch_bounds__(1024) void scan_kernel(const int* __restrict__ mask,
                                                    int* __restrict__ rowidx,
                                                    int* __restrict__ jof,
                                                    int* __restrict__ nkeep) {
    int t = threadIdx.x;              // 0..1023, 32 consecutive ints each
    int base = t * 32;
    unsigned flags = 0;
    int cnt = 0;
    const int4* m4 = reinterpret_cast<const int4*>(mask + base);
#pragma unroll
    for (int v = 0; v < 8; ++v) {
        int4 x = m4[v];
        if (x.x == 0) { flags |= 1u << (v * 4 + 0); cnt++; }
        if (x.y == 0) { flags |= 1u << (v * 4 + 1); cnt++; }
        if (x.z == 0) { flags |= 1u << (v * 4 + 2); cnt++; }
        if (x.w == 0) { flags |= 1u << (v * 4 + 3); cnt++; }
    }
    int lane = t & 63, wv = t >> 6;
    int inc = cnt;
    for (int off = 1; off < 64; off <<= 1) {
        int o = __shfl_up(inc, off);
        if (lane >= off) inc += o;
    }
    __shared__ int wsum[16], wbase[16];
    if (lane == 63) wsum[wv] = inc;
    __syncthreads();
    if (t == 0) {
        int acc = 0;
        for (int w = 0; w < 16; ++w) { wbase[w] = acc; acc += wsum[w]; }
        nkeep[0] = acc;
    }
    __syncthreads();
    int e = wbase[wv] + inc - cnt;
#pragma unroll
    for (int i = 0; i < 32; ++i) {
        if ((flags >> i) & 1u) {
            int l = base + i;
            int m = ((l & 2047) << 4) | (l >> 11);   // m = s*16 + b
            rowidx[e] = m;
            jof[m] = e;
            e++;
        }
    }
}

// ---------------- kernel 1: fused prep = compact-conv_enc + conv_we + qk ----------------
__global__ __launch_bounds__(256) void prep_all(const float* __restrict__ hidden,
                                                const float* __restrict__ enc,
                                                const float* __restrict__ attn_w,
                                                const float* __restrict__ attn_b,
                                                const int* __restrict__ rowidx,
                                                const int* __restrict__ nkp,
                                                float* __restrict__ q,
                                                __hip_bfloat16* __restrict__ web,
                                                __hip_bfloat16* __restrict__ encb) {
    int bid = blockIdx.x;
    if (bid < NB_ENC) {
        int nkeep = nkp[0];
        int npad = (nkeep + 255) & ~255;
        int plim = npad > MMAIN ? npad : MMAIN;    // main gemm always reads rows [0, MMAIN)
        int j = bid * 2 + (threadIdx.x >> 7);      // 2 rows per block
        if (j >= plim) return;
        int col = (threadIdx.x & 127) * 8;
        unsigned short* dst = (unsigned short*)encb + (size_t)j * HDIM + col;
        if (j >= nkeep) {
            short8 z = (short8)0;
            *reinterpret_cast<short8*>(dst) = z;
            return;
        }
        int m = rowidx[j];
        const float4* s4 = reinterpret_cast<const float4*>(enc + (size_t)m * HDIM + col);
        float4 a = s4[0], b = s4[1];
        union { unsigned short u[8]; short8 v; } cv;
        cv.u[0] = f2bf(a.x); cv.u[1] = f2bf(a.y); cv.u[2] = f2bf(a.z); cv.u[3] = f2bf(a.w);
        cv.u[4] = f2bf(b.x); cv.u[5] = f2bf(b.y); cv.u[6] = f2bf(b.z); cv.u[7] = f2bf(b.w);
        *reinterpret_cast<short8*>(dst) = cv.v;
        return;
    }
    if (bid < NB_ENC + NB_WE) {
        size_t i0 = ((size_t)(bid - NB_ENC) * 256 + threadIdx.x) * 8;
        int n = (int)(i0 >> 10);
        int h = (int)(i0 & 1023);
        const float4* src = reinterpret_cast<const float4*>(attn_w + (size_t)n * (2 * HDIM) + HDIM + h);
        float4 a = src[0], b = src[1];
        union { unsigned short u[8]; short8 v; } cv;
        cv.u[0] = f2bf(a.x); cv.u[1] = f2bf(a.y); cv.u[2] = f2bf(a.z); cv.u[3] = f2bf(a.w);
        cv.u[4] = f2bf(b.x); cv.u[5] = f2bf(b.y); cv.u[6] = f2bf(b.z); cv.u[7] = f2bf(b.w);
        *reinterpret_cast<short8*>((unsigned short*)web + i0) = cv.v;
        return;
    }
    int k = bid - (NB_ENC + NB_WE);
    int tid = threadIdx.x;
    const float* w = attn_w + (size_t)k * (2 * HDIM);
    float p[BATCH];
#pragma unroll
    for (int b = 0; b < BATCH; b++) p[b] = 0.f;
    for (int h = tid; h < HDIM; h += 256) {
        float wv = w[h];
#pragma unroll
        for (int b = 0; b < BATCH; b++) p[b] += hidden[b * HDIM + h] * wv;
    }
#pragma unroll
    for (int b = 0; b < BATCH; b++) {
        for (int off = 32; off; off >>= 1) p[b] += __shfl_down(p[b], off);
    }
    __shared__ float red[4][BATCH];
    int lane = tid & 63, wid = tid >> 6;
    if (lane == 0) {
#pragma unroll
        for (int b = 0; b < BATCH; b++) red[wid][b] = p[b];
    }
    __syncthreads();
    if (tid < BATCH) {
        float s = red[0][tid] + red[1][tid] + red[2][tid] + red[3][tid] + attn_b[k];
        q[(size_t)tid * HDIM + k] = s;
    }
}

// ---------------- kernel 2: 256x256 GEMM over rows [0, MMAIN), EXACTLY 256 tiles ----------------
// K-loop/epilogue identical to verified R15/R19 machinery; fixed grid = one tile round.
__global__ __launch_bounds__(512, 2) void gemm8(const __hip_bfloat16* __restrict__ encb,
                                                const __hip_bfloat16* __restrict__ web,
                                                const float* __restrict__ qv,
                                                const float* __restrict__ score_w,
                                                const int* __restrict__ rowidx,
                                                const int* __restrict__ nkp,
                                                float* __restrict__ part) {
    __shared__ __align__(16) char pool[163840];

    int tid = threadIdx.x;
    int lane = tid & 63;
    int wid = tid >> 6;        // 0..7
    int wr = wid >> 2;         // 0..1  M half
    int wc = wid & 3;          // 0..3  N quarter

    // 256 blocks = 8 XCDs x 32; XCD x owns bm in [x*8, x*8+8), bn fastest (A-quartets co-XCD)
    int bid = blockIdx.x;
    int lin = (bid & 7) * 32 + (bid >> 3);
    int bm = lin >> 2;         // 0..63
    int bn = lin & 3;          // 0..3
    int m0 = bm * BM, n0 = bn * BN;

    int nkeep = nkp[0];

    int srow = tid >> 3;
    int scolb = (((tid & 7) ^ ((tid >> 3) & 7)) << 4);
    const char* eb = (const char*)encb;
    const char* wb = (const char*)web;

    auto STG = [&](const char* g, int ldsoff) {
        GLD16(g + (size_t)srow * 2048 + scolb, pool + ldsoff + wid * 1024);
        GLD16(g + (size_t)(srow + 64) * 2048 + scolb, pool + ldsoff + 8192 + wid * 1024);
    };
    auto APTR = [&](int kt, int h) { return eb + ((size_t)(m0 + h * 128) * HDIM + kt * BKT) * 2; };
    auto BPTR = [&](int kt, int h) { return wb + ((size_t)(n0 + h * 128) * HDIM + kt * BKT) * 2; };
#define ALDS(par, h) ((par) * 32768 + (h) * 16384)
#define BLDS(buf, h) (65536 + (buf) * 32768 + (h) * 16384)

    int lq = lane & 15, lh = lane >> 4;
    int flip = (lane & 7) << 4;
    int pks0 = lq * 128 + ((lh * 16) ^ flip);
    int pks1 = lq * 128 + (((64 + lh * 16)) ^ flip);
    int aFB = wr * 16384;
    int bOFF = (wc >> 1) * 16384 + (wc & 1) * 8192;

    f32x4 acc[8][4];
#pragma unroll
    for (int i = 0; i < 8; i++)
#pragma unroll
        for (int j = 0; j < 4; j++) acc[i][j] = (f32x4)0.f;
    short8 br[4][2];

#define RD8(off) (*reinterpret_cast<const short8*>(pool + (off)))

#define CLUSTER(Q, PAR, BB, STAGE_STMT)                                                   \
    {                                                                                     \
        if ((Q) == 0) {                                                                   \
            _Pragma("unroll") for (int nj = 0; nj < 4; ++nj) {                            \
                br[nj][0] = RD8(65536 + (BB) * 32768 + bOFF + nj * 2048 + pks0);          \
                br[nj][1] = RD8(65536 + (BB) * 32768 + bOFF + nj * 2048 + pks1);          \
            }                                                                             \
        }                                                                                 \
        short8 a0k0 = RD8(aFB + (PAR) * 32768 + (2 * (Q)) * 2048 + pks0);                 \
        short8 a0k1 = RD8(aFB + (PAR) * 32768 + (2 * (Q)) * 2048 + pks1);                 \
        short8 a1k0 = RD8(aFB + (PAR) * 32768 + (2 * (Q) + 1) * 2048 + pks0);             \
        short8 a1k1 = RD8(aFB + (PAR) * 32768 + (2 * (Q) + 1) * 2048 + pks1);             \
        STAGE_STMT;                                                                       \
        __builtin_amdgcn_s_setprio(1);                                                    \
        _Pragma("unroll") for (int nj = 0; nj < 4; ++nj) {                                \
            acc[2 * (Q)][nj] = __builtin_amdgcn_mfma_f32_16x16x32_bf16(a0k0, br[nj][0], acc[2 * (Q)][nj], 0, 0, 0); \
            acc[2 * (Q)][nj] = __builtin_amdgcn_mfma_f32_16x16x32_bf16(a0k1, br[nj][1], acc[2 * (Q)][nj], 0, 0, 0); \
            acc[2 * (Q) + 1][nj] = __builtin_amdgcn_mfma_f32_16x16x32_bf16(a1k0, br[nj][0], acc[2 * (Q) + 1][nj], 0, 0, 0); \
            acc[2 * (Q) + 1][nj] = __builtin_amdgcn_mfma_f32_16x16x32_bf16(a1k1, br[nj][1], acc[2 * (Q) + 1][nj], 0, 0, 0); \
        }                                                                                 \
        __builtin_amdgcn_s_setprio(0);                                                    \
    }

#define TILE(PAR, BB, S1, S2, S3, S4, CLOSE)                                              \
    {                                                                                     \
        CLUSTER(0, PAR, BB, S1);                                                          \
        CLUSTER(1, PAR, BB, S2);                                                          \
        CLUSTER(2, PAR, BB, S3);                                                          \
        CLUSTER(3, PAR, BB, S4);                                                          \
        CLOSE;                                                                            \
        __builtin_amdgcn_s_barrier();                                                     \
        __builtin_amdgcn_sched_barrier(0);                                                \
    }

    STG(APTR(0, 0), ALDS(0, 0));
    STG(APTR(0, 1), ALDS(0, 1));
    STG(BPTR(0, 0), BLDS(0, 0));
    STG(BPTR(0, 1), BLDS(0, 1));
    STG(BPTR(1, 0), BLDS(1, 0));
    STG(BPTR(1, 1), BLDS(1, 1));
    VMC(4);
    __builtin_amdgcn_s_barrier();
    __builtin_amdgcn_sched_barrier(0);

#pragma unroll 1
    for (int J = 0; J < 2; ++J) {
        int t = 6 * J;
        TILE(0, 0, STG(APTR(t + 1, 0), ALDS(1, 0)), STG(APTR(t + 1, 1), ALDS(1, 1)),
                   STG(BPTR(t + 2, 0), BLDS(2, 0)), STG(BPTR(t + 2, 1), BLDS(2, 1)), VMC(4));
        TILE(1, 1, STG(APTR(t + 2, 0), ALDS(0, 0)), STG(APTR(t + 2, 1), ALDS(0, 1)),
                   STG(BPTR(t + 3, 0), BLDS(0, 0)), STG(BPTR(t + 3, 1), BLDS(0, 1)), VMC(4));
        TILE(0, 2, STG(APTR(t + 3, 0), ALDS(1, 0)), STG(APTR(t + 3, 1), ALDS(1, 1)),
                   STG(BPTR(t + 4, 0), BLDS(1, 0)), STG(BPTR(t + 4, 1), BLDS(1, 1)), VMC(4));
        TILE(1, 0, STG(APTR(t + 4, 0), ALDS(0, 0)), STG(APTR(t + 4, 1), ALDS(0, 1)),
                   STG(BPTR(t + 5, 0), BLDS(2, 0)), STG(BPTR(t + 5, 1), BLDS(2, 1)), VMC(4));
        TILE(0, 1, STG(APTR(t + 5, 0), ALDS(1, 0)), STG(APTR(t + 5, 1), ALDS(1, 1)),
                   STG(BPTR(t + 6, 0), BLDS(0, 0)), STG(BPTR(t + 6, 1), BLDS(0, 1)), VMC(4));
        TILE(1, 2, STG(APTR(t + 6, 0), ALDS(0, 0)), STG(APTR(t + 6, 1), ALDS(0, 1)),
                   STG(BPTR(t + 7, 0), BLDS(1, 0)), STG(BPTR(t + 7, 1), BLDS(1, 1)), VMC(4));
    }
    TILE(0, 0, STG(APTR(13, 0), ALDS(1, 0)), STG(APTR(13, 1), ALDS(1, 1)),
               STG(BPTR(14, 0), BLDS(2, 0)), STG(BPTR(14, 1), BLDS(2, 1)), VMC(4));
    TILE(1, 1, STG(APTR(14, 0), ALDS(0, 0)), STG(APTR(14, 1), ALDS(0, 1)),
               STG(BPTR(15, 0), BLDS(0, 0)), STG(BPTR(15, 1), BLDS(0, 1)), VMC(4));
    TILE(0, 2, STG(APTR(15, 0), ALDS(1, 0)), STG(APTR(15, 1), ALDS(1, 1)), , , VMC(0));
    TILE(1, 0, , , , , );

    // ---- fused epilogue: LDS transpose-reduce with per-row batch table ----
    float* q_lds = reinterpret_cast<float*>(pool);            // [16][256]
    float* sc_lds = reinterpret_cast<float*>(pool + 16384);   // [256]
    int* rowb = reinterpret_cast<int*>(pool + 17408);         // [256]
    float* red = reinterpret_cast<float*>(pool + 18432);      // [4][256][20]
    {
        int qb = tid >> 5;
        int kl = (tid & 31) * 8;
        const float4* src = reinterpret_cast<const float4*>(qv + (size_t)qb * HDIM + n0 + kl);
        float4 v0 = src[0], v1 = src[1];
        *reinterpret_cast<float4*>(&q_lds[qb * 256 + kl]) = v0;
        *reinterpret_cast<float4*>(&q_lds[qb * 256 + kl + 4]) = v1;
        if (tid < BN) sc_lds[tid] = score_w[n0 + tid];
        if (tid < BM) rowb[tid] = (m0 + tid < nkeep) ? (rowidx[m0 + tid] & 15) : 0;
    }
    __syncthreads();

#pragma unroll
    for (int mi = 0; mi < 8; ++mi) {
#pragma unroll
        for (int r = 0; r < 4; ++r) {
            int row = wr * 128 + mi * 16 + lh * 4 + r;
            int bq = rowb[row];
            float s = 0.f;
#pragma unroll
            for (int nj = 0; nj < 4; ++nj) {
                int kl = wc * 64 + nj * 16 + lq;
                float v = acc[mi][nj][r] + q_lds[bq * 256 + kl];
                float t = 1.f - 2.f / (__expf(2.f * v) + 1.f);  // tanh(v)
                s += sc_lds[kl] * t;
            }
            red[(wc * 256 + row) * 20 + lq] = s;
        }
    }
    __syncthreads();
    if (tid < BM) {
        float t = 0.f;
#pragma unroll
        for (int w4 = 0; w4 < 4; ++w4) {
            const f32x4* p = reinterpret_cast<const f32x4*>(&red[(w4 * 256 + tid) * 20]);
#pragma unroll
            for (int i = 0; i < 4; ++i) {
                f32x4 v = p[i];
                t += v[0] + v[1] + v[2] + v[3];
            }
        }
        part[(size_t)bn * M_TOT + m0 + tid] = t;
    }
#undef CLUSTER
#undef TILE
#undef RD8
#undef ALDS
#undef BLDS
}

// ---------------- kernel 2b: remainder rows [MMAIN, nkeep) — naive 32x256 MFMA tiles ----------
// Operands straight from L2 (web 2MB hot; enc rows 2KB). Writes same part[c][j] layout.
__global__ __launch_bounds__(256) void rem_kernel(const __hip_bfloat16* __restrict__ encb,
                                                  const __hip_bfloat16* __restrict__ web,
                                                  const float* __restrict__ qv,
                                                  const float* __restrict__ score_w,
                                                  const int* __restrict__ rowidx,
                                                  const int* __restrict__ nkp,
                                                  float* __restrict__ part) {
    int nkeep = nkp[0];
    int bid = blockIdx.x;
    int mt = bid >> 2, bn = bid & 3;
    int j0 = MMAIN + mt * 32;
    if (j0 >= nkeep) return;

    int tid = threadIdx.x, lane = tid & 63, w = tid >> 6;   // 4 waves
    int lq = lane & 15, lh = lane >> 4;
    int colblk = bn * 256 + w * 64;

    f32x4 acc[2][4];
#pragma unroll
    for (int i = 0; i < 2; i++)
#pragma unroll
        for (int j = 0; j < 4; j++) acc[i][j] = (f32x4)0.f;

    for (int kt = 0; kt < 32; ++kt) {
        int kb = kt * 32 + lh * 8;
        short8 a0 = *reinterpret_cast<const short8*>(encb + (size_t)(j0 + lq) * HDIM + kb);
        short8 a1 = *reinterpret_cast<const short8*>(encb + (size_t)(j0 + 16 + lq) * HDIM + kb);
#pragma unroll
        for (int nj = 0; nj < 4; ++nj) {
            short8 b = *reinterpret_cast<const short8*>(web + (size_t)(colblk + nj * 16 + lq) * HDIM + kb);
            acc[0][nj] = __builtin_amdgcn_mfma_f32_16x16x32_bf16(a0, b, acc[0][nj], 0, 0, 0);
            acc[1][nj] = __builtin_amdgcn_mfma_f32_16x16x32_bf16(a1, b, acc[1][nj], 0, 0, 0);
        }
    }

    __shared__ float eng[4][32];
#pragma unroll
    for (int mi = 0; mi < 2; ++mi) {
#pragma unroll
        for (int r = 0; r < 4; ++r) {
            int row = mi * 16 + lh * 4 + r;
            int j = j0 + row;
            int bq = (j < nkeep) ? (rowidx[j] & 15) : 0;
            float s = 0.f;
#pragma unroll
            for (int nj = 0; nj < 4; ++nj) {
                int kl = colblk + nj * 16 + lq;
                float v = acc[mi][nj][r] + qv[(size_t)bq * HDIM + kl];
                float t = 1.f - 2.f / (__expf(2.f * v) + 1.f);  // tanh(v)
                s += score_w[kl] * t;
            }
            for (int off = 1; off < 16; off <<= 1) s += __shfl_xor(s, off);
            if (lq == 0) eng[w][row] = s;
        }
    }
    __syncthreads();
    if (tid < 32) {
        float t = eng[0][tid] + eng[1][tid] + eng[2][tid] + eng[3][tid];
        part[(size_t)bn * M_TOT + j0 + tid] = t;
    }
}

// ---------------- kernel 3: gather partials via jof + mask + softmax over S ----------------
__global__ __launch_bounds__(256) void softmax_kernel(const float* __restrict__ part,
                                                      const int* __restrict__ mask,
                                                      const int* __restrict__ jof,
                                                      float* __restrict__ out) {
    int b = blockIdx.x;
    int tid = threadIdx.x;
    __shared__ float e_lds[SEQ];
    __shared__ float red[4], red2[4];
    int lane = tid & 63, wid = tid >> 6;
    float lmax = -3.4e38f;
    for (int it = 0; it < SEQ / 256; ++it) {
        int s = it * 256 + tid;
        float e = -1e12f;
        if (!mask[(size_t)b * SEQ + s]) {
            int m = s * BATCH + b;
            int j = jof[m];
            float acc = 0.f;
#pragma unroll
            for (int c = 0; c < NBLK; c++) acc += part[(size_t)c * M_TOT + j];
            e = acc;
        }
        e_lds[s] = e;
        lmax = fmaxf(lmax, e);
    }
    for (int off = 32; off; off >>= 1) lmax = fmaxf(lmax, __shfl_xor(lmax, off));
    if (lane == 0) red[wid] = lmax;
    __syncthreads();
    float gmax = fmaxf(fmaxf(red[0], red[1]), fmaxf(red[2], red[3]));
    float lsum = 0.f;
    for (int it = 0; it < SEQ / 256; ++it) {
        int s = it * 256 + tid;
        float p = __expf(e_lds[s] - gmax);
        e_lds[s] = p;
        lsum += p;
    }
    for (int off = 32; off; off >>= 1) lsum += __shfl_xor(lsum, off);
    if (lane == 0) red2[wid] = lsum;
    __syncthreads();
    float inv = 1.f / (red2[0] + red2[1] + red2[2] + red2[3]);
    for (int it = 0; it < SEQ / 256; ++it) {
        int s = it * 256 + tid;
        out[(size_t)b * SEQ + s] = e_lds[s] * inv;
    }
}

extern "C" void kernel_launch(void* const* d_in, const int* in_sizes, int n_in,
                              void* d_out, int out_size, void* d_ws, size_t ws_size,
                              hipStream_t stream) {
    const float* hidden   = (const float*)d_in[0];
    const float* enc      = (const float*)d_in[1];
    const int*   seq_mask = (const int*)d_in[2];
    const float* attn_w   = (const float*)d_in[3];
    const float* attn_b   = (const float*)d_in[4];
    const float* score_w  = (const float*)d_in[5];
    float* out = (float*)d_out;

    char* ws = (char*)d_ws;
    float* q = (float*)ws;                                            // 64 KB
    __hip_bfloat16* web = (__hip_bfloat16*)(ws + 65536);              // 2 MB
    float* part = (float*)(ws + 65536 + 2 * 1024 * 1024);             // 512 KB
    int* rowidx = (int*)(ws + 65536 + 2 * 1024 * 1024 + 512 * 1024);  // 128 KB
    int* jof    = (int*)(ws + 65536 + 2 * 1024 * 1024 + 640 * 1024);  // 128 KB
    int* nkeep  = (int*)(ws + 65536 + 2 * 1024 * 1024 + 768 * 1024);  // 4 B
    __hip_bfloat16* encb = (__hip_bfloat16*)(ws + 65536 + 3 * 1024 * 1024);  // 64 MB

    scan_kernel<<<dim3(1), dim3(1024), 0, stream>>>(seq_mask, rowidx, jof, nkeep);
    prep_all<<<dim3(NB_ENC + NB_WE + NB_QK), dim3(256), 0, stream>>>(hidden, enc, attn_w, attn_b,
                                                                     rowidx, nkeep, q, web, encb);
    gemm8<<<dim3(256), dim3(512), 0, stream>>>(encb, web, q, score_w, rowidx, nkeep, part);
    rem_kernel<<<dim3(2048), dim3(256), 0, stream>>>(encb, web, q, score_w, rowidx, nkeep, part);
    softmax_kernel<<<dim3(BATCH), dim3(256), 0, stream>>>(part, seq_mask, jof, out);
}

// Round 21
// 114.038 us; speedup vs baseline: 1.0852x; 1.0799x over previous
//
#include <hip/hip_runtime.h>
#include <hip/hip_bf16.h>

#define HDIM 1024
#define SEQ 2048
#define BATCH 16
#define M_TOT (SEQ*BATCH)   // 32768
#define NBLK 4              // N split into 4 chunks of 256
#define BM 256
#define BN 256
#define BKT 64              // K-tile depth
#define NT (HDIM/BKT)       // 16 K-tiles
#define MMAIN 16384         // rows handled by the main 256-tile gemm (64 M-tiles)

// prep_all grid layout
#define NB_ENC ((M_TOT*HDIM)/(8*256))   // 16384
#define NB_WE  ((HDIM*HDIM)/(8*256))    // 512
#define NB_QK  (HDIM)                   // 1024

typedef __attribute__((ext_vector_type(8))) short short8;
typedef __attribute__((ext_vector_type(4))) float f32x4;

typedef const void __attribute__((address_space(1))) gvoid_t;
typedef void __attribute__((address_space(3))) svoid_t;
#define GLD16(gp, lp) __builtin_amdgcn_global_load_lds((gvoid_t*)(gp), (svoid_t*)(lp), 16, 0, 0)
#define VMC(N) asm volatile("s_waitcnt vmcnt(" #N ")" ::: "memory")

static __device__ __forceinline__ unsigned short f2bf(float f) {
    unsigned int x = __float_as_uint(f);
    unsigned int r = (x + 0x7FFFu + ((x >> 16) & 1u)) >> 16;  // RNE
    return (unsigned short)r;
}

// ---------------- compaction, parallel 3-phase (l-ascending order, same as R20) ----------------
// scanA: counts[c] = #kept in 256-int chunk c (128 blocks x 256 thr)
__global__ __launch_bounds__(256) void scanA(const int* __restrict__ mask,
                                             int* __restrict__ counts) {
    int idx = blockIdx.x * 256 + threadIdx.x;
    int flag = (mask[idx] == 0) ? 1 : 0;
    unsigned long long bal = __ballot(flag);
    __shared__ int wsum[4];
    int lane = threadIdx.x & 63, wv = threadIdx.x >> 6;
    if (lane == 0) wsum[wv] = __popcll(bal);
    __syncthreads();
    if (threadIdx.x == 0) counts[blockIdx.x] = wsum[0] + wsum[1] + wsum[2] + wsum[3];
}

// scanB: exclusive prefix over 128 counts -> bases; nkeep = total (1 tiny block)
__global__ __launch_bounds__(64) void scanB(const int* __restrict__ counts,
                                            int* __restrict__ bases,
                                            int* __restrict__ nkeep) {
    if (threadIdx.x == 0) {
        int acc = 0;
        for (int c = 0; c < 128; ++c) { bases[c] = acc; acc += counts[c]; }
        nkeep[0] = acc;
    }
}

// scanC: scatter rowidx/jof using bases (128 blocks; writes spread over many CUs)
__global__ __launch_bounds__(256) void scanC(const int* __restrict__ mask,
                                             const int* __restrict__ bases,
                                             int* __restrict__ rowidx,
                                             int* __restrict__ jof) {
    int idx = blockIdx.x * 256 + threadIdx.x;
    int flag = (mask[idx] == 0) ? 1 : 0;
    unsigned long long bal = __ballot(flag);
    int lane = threadIdx.x & 63, wv = threadIdx.x >> 6;
    __shared__ int wsum[4];
    if (lane == 0) wsum[wv] = __popcll(bal);
    __syncthreads();
    int wbase = bases[blockIdx.x];
    for (int w = 0; w < 4; ++w) if (w < wv) wbase += wsum[w];
    if (flag) {
        int excl = __popcll(bal & ((1ull << lane) - 1ull));
        int e = wbase + excl;
        int l = idx;
        int m = ((l & 2047) << 4) | (l >> 11);   // m = s*16 + b
        rowidx[e] = m;
        jof[m] = e;
    }
}

// ---------------- kernel 1: fused prep = compact-conv_enc + conv_we + qk ----------------
__global__ __launch_bounds__(256) void prep_all(const float* __restrict__ hidden,
                                                const float* __restrict__ enc,
                                                const float* __restrict__ attn_w,
                                                const float* __restrict__ attn_b,
                                                const int* __restrict__ rowidx,
                                                const int* __restrict__ nkp,
                                                float* __restrict__ q,
                                                __hip_bfloat16* __restrict__ web,
                                                __hip_bfloat16* __restrict__ encb) {
    int bid = blockIdx.x;
    if (bid < NB_ENC) {
        int nkeep = nkp[0];
        int npad = (nkeep + 255) & ~255;
        int plim = npad > MMAIN ? npad : MMAIN;    // main gemm always reads rows [0, MMAIN)
        int j = bid * 2 + (threadIdx.x >> 7);      // 2 rows per block
        if (j >= plim) return;
        int col = (threadIdx.x & 127) * 8;
        unsigned short* dst = (unsigned short*)encb + (size_t)j * HDIM + col;
        if (j >= nkeep) {
            short8 z = (short8)0;
            *reinterpret_cast<short8*>(dst) = z;
            return;
        }
        int m = rowidx[j];
        const float4* s4 = reinterpret_cast<const float4*>(enc + (size_t)m * HDIM + col);
        float4 a = s4[0], b = s4[1];
        union { unsigned short u[8]; short8 v; } cv;
        cv.u[0] = f2bf(a.x); cv.u[1] = f2bf(a.y); cv.u[2] = f2bf(a.z); cv.u[3] = f2bf(a.w);
        cv.u[4] = f2bf(b.x); cv.u[5] = f2bf(b.y); cv.u[6] = f2bf(b.z); cv.u[7] = f2bf(b.w);
        *reinterpret_cast<short8*>(dst) = cv.v;
        return;
    }
    if (bid < NB_ENC + NB_WE) {
        size_t i0 = ((size_t)(bid - NB_ENC) * 256 + threadIdx.x) * 8;
        int n = (int)(i0 >> 10);
        int h = (int)(i0 & 1023);
        const float4* src = reinterpret_cast<const float4*>(attn_w + (size_t)n * (2 * HDIM) + HDIM + h);
        float4 a = src[0], b = src[1];
        union { unsigned short u[8]; short8 v; } cv;
        cv.u[0] = f2bf(a.x); cv.u[1] = f2bf(a.y); cv.u[2] = f2bf(a.z); cv.u[3] = f2bf(a.w);
        cv.u[4] = f2bf(b.x); cv.u[5] = f2bf(b.y); cv.u[6] = f2bf(b.z); cv.u[7] = f2bf(b.w);
        *reinterpret_cast<short8*>((unsigned short*)web + i0) = cv.v;
        return;
    }
    int k = bid - (NB_ENC + NB_WE);
    int tid = threadIdx.x;
    const float* w = attn_w + (size_t)k * (2 * HDIM);
    float p[BATCH];
#pragma unroll
    for (int b = 0; b < BATCH; b++) p[b] = 0.f;
    for (int h = tid; h < HDIM; h += 256) {
        float wv = w[h];
#pragma unroll
        for (int b = 0; b < BATCH; b++) p[b] += hidden[b * HDIM + h] * wv;
    }
#pragma unroll
    for (int b = 0; b < BATCH; b++) {
        for (int off = 32; off; off >>= 1) p[b] += __shfl_down(p[b], off);
    }
    __shared__ float red[4][BATCH];
    int lane = tid & 63, wid = tid >> 6;
    if (lane == 0) {
#pragma unroll
        for (int b = 0; b < BATCH; b++) red[wid][b] = p[b];
    }
    __syncthreads();
    if (tid < BATCH) {
        float s = red[0][tid] + red[1][tid] + red[2][tid] + red[3][tid] + attn_b[k];
        q[(size_t)tid * HDIM + k] = s;
    }
}

// ---------------- kernel 2: 256x256 GEMM over rows [0, MMAIN), EXACTLY 256 tiles ----------------
__global__ __launch_bounds__(512, 2) void gemm8(const __hip_bfloat16* __restrict__ encb,
                                                const __hip_bfloat16* __restrict__ web,
                                                const float* __restrict__ qv,
                                                const float* __restrict__ score_w,
                                                const int* __restrict__ rowidx,
                                                const int* __restrict__ nkp,
                                                float* __restrict__ part) {
    __shared__ __align__(16) char pool[163840];

    int tid = threadIdx.x;
    int lane = tid & 63;
    int wid = tid >> 6;        // 0..7
    int wr = wid >> 2;         // 0..1  M half
    int wc = wid & 3;          // 0..3  N quarter

    // 256 blocks = 8 XCDs x 32; XCD x owns bm in [x*8, x*8+8), bn fastest
    int bid = blockIdx.x;
    int lin = (bid & 7) * 32 + (bid >> 3);
    int bm = lin >> 2;         // 0..63
    int bn = lin & 3;          // 0..3
    int m0 = bm * BM, n0 = bn * BN;

    int nkeep = nkp[0];

    int srow = tid >> 3;
    int scolb = (((tid & 7) ^ ((tid >> 3) & 7)) << 4);
    const char* eb = (const char*)encb;
    const char* wb = (const char*)web;

    auto STG = [&](const char* g, int ldsoff) {
        GLD16(g + (size_t)srow * 2048 + scolb, pool + ldsoff + wid * 1024);
        GLD16(g + (size_t)(srow + 64) * 2048 + scolb, pool + ldsoff + 8192 + wid * 1024);
    };
    auto APTR = [&](int kt, int h) { return eb + ((size_t)(m0 + h * 128) * HDIM + kt * BKT) * 2; };
    auto BPTR = [&](int kt, int h) { return wb + ((size_t)(n0 + h * 128) * HDIM + kt * BKT) * 2; };
#define ALDS(par, h) ((par) * 32768 + (h) * 16384)
#define BLDS(buf, h) (65536 + (buf) * 32768 + (h) * 16384)

    int lq = lane & 15, lh = lane >> 4;
    int flip = (lane & 7) << 4;
    int pks0 = lq * 128 + ((lh * 16) ^ flip);
    int pks1 = lq * 128 + (((64 + lh * 16)) ^ flip);
    int aFB = wr * 16384;
    int bOFF = (wc >> 1) * 16384 + (wc & 1) * 8192;

    f32x4 acc[8][4];
#pragma unroll
    for (int i = 0; i < 8; i++)
#pragma unroll
        for (int j = 0; j < 4; j++) acc[i][j] = (f32x4)0.f;
    short8 br[4][2];

#define RD8(off) (*reinterpret_cast<const short8*>(pool + (off)))

#define CLUSTER(Q, PAR, BB, STAGE_STMT)                                                   \
    {                                                                                     \
        if ((Q) == 0) {                                                                   \
            _Pragma("unroll") for (int nj = 0; nj < 4; ++nj) {                            \
                br[nj][0] = RD8(65536 + (BB) * 32768 + bOFF + nj * 2048 + pks0);          \
                br[nj][1] = RD8(65536 + (BB) * 32768 + bOFF + nj * 2048 + pks1);          \
            }                                                                             \
        }                                                                                 \
        short8 a0k0 = RD8(aFB + (PAR) * 32768 + (2 * (Q)) * 2048 + pks0);                 \
        short8 a0k1 = RD8(aFB + (PAR) * 32768 + (2 * (Q)) * 2048 + pks1);                 \
        short8 a1k0 = RD8(aFB + (PAR) * 32768 + (2 * (Q) + 1) * 2048 + pks0);             \
        short8 a1k1 = RD8(aFB + (PAR) * 32768 + (2 * (Q) + 1) * 2048 + pks1);             \
        STAGE_STMT;                                                                       \
        __builtin_amdgcn_s_setprio(1);                                                    \
        _Pragma("unroll") for (int nj = 0; nj < 4; ++nj) {                                \
            acc[2 * (Q)][nj] = __builtin_amdgcn_mfma_f32_16x16x32_bf16(a0k0, br[nj][0], acc[2 * (Q)][nj], 0, 0, 0); \
            acc[2 * (Q)][nj] = __builtin_amdgcn_mfma_f32_16x16x32_bf16(a0k1, br[nj][1], acc[2 * (Q)][nj], 0, 0, 0); \
            acc[2 * (Q) + 1][nj] = __builtin_amdgcn_mfma_f32_16x16x32_bf16(a1k0, br[nj][0], acc[2 * (Q) + 1][nj], 0, 0, 0); \
            acc[2 * (Q) + 1][nj] = __builtin_amdgcn_mfma_f32_16x16x32_bf16(a1k1, br[nj][1], acc[2 * (Q) + 1][nj], 0, 0, 0); \
        }                                                                                 \
        __builtin_amdgcn_s_setprio(0);                                                    \
    }

#define TILE(PAR, BB, S1, S2, S3, S4, CLOSE)                                              \
    {                                                                                     \
        CLUSTER(0, PAR, BB, S1);                                                          \
        CLUSTER(1, PAR, BB, S2);                                                          \
        CLUSTER(2, PAR, BB, S3);                                                          \
        CLUSTER(3, PAR, BB, S4);                                                          \
        CLOSE;                                                                            \
        __builtin_amdgcn_s_barrier();                                                     \
        __builtin_amdgcn_sched_barrier(0);                                                \
    }

    STG(APTR(0, 0), ALDS(0, 0));
    STG(APTR(0, 1), ALDS(0, 1));
    STG(BPTR(0, 0), BLDS(0, 0));
    STG(BPTR(0, 1), BLDS(0, 1));
    STG(BPTR(1, 0), BLDS(1, 0));
    STG(BPTR(1, 1), BLDS(1, 1));
    VMC(4);
    __builtin_amdgcn_s_barrier();
    __builtin_amdgcn_sched_barrier(0);

#pragma unroll 1
    for (int J = 0; J < 2; ++J) {
        int t = 6 * J;
        TILE(0, 0, STG(APTR(t + 1, 0), ALDS(1, 0)), STG(APTR(t + 1, 1), ALDS(1, 1)),
                   STG(BPTR(t + 2, 0), BLDS(2, 0)), STG(BPTR(t + 2, 1), BLDS(2, 1)), VMC(4));
        TILE(1, 1, STG(APTR(t + 2, 0), ALDS(0, 0)), STG(APTR(t + 2, 1), ALDS(0, 1)),
                   STG(BPTR(t + 3, 0), BLDS(0, 0)), STG(BPTR(t + 3, 1), BLDS(0, 1)), VMC(4));
        TILE(0, 2, STG(APTR(t + 3, 0), ALDS(1, 0)), STG(APTR(t + 3, 1), ALDS(1, 1)),
                   STG(BPTR(t + 4, 0), BLDS(1, 0)), STG(BPTR(t + 4, 1), BLDS(1, 1)), VMC(4));
        TILE(1, 0, STG(APTR(t + 4, 0), ALDS(0, 0)), STG(APTR(t + 4, 1), ALDS(0, 1)),
                   STG(BPTR(t + 5, 0), BLDS(2, 0)), STG(BPTR(t + 5, 1), BLDS(2, 1)), VMC(4));
        TILE(0, 1, STG(APTR(t + 5, 0), ALDS(1, 0)), STG(APTR(t + 5, 1), ALDS(1, 1)),
                   STG(BPTR(t + 6, 0), BLDS(0, 0)), STG(BPTR(t + 6, 1), BLDS(0, 1)), VMC(4));
        TILE(1, 2, STG(APTR(t + 6, 0), ALDS(0, 0)), STG(APTR(t + 6, 1), ALDS(0, 1)),
                   STG(BPTR(t + 7, 0), BLDS(1, 0)), STG(BPTR(t + 7, 1), BLDS(1, 1)), VMC(4));
    }
    TILE(0, 0, STG(APTR(13, 0), ALDS(1, 0)), STG(APTR(13, 1), ALDS(1, 1)),
               STG(BPTR(14, 0), BLDS(2, 0)), STG(BPTR(14, 1), BLDS(2, 1)), VMC(4));
    TILE(1, 1, STG(APTR(14, 0), ALDS(0, 0)), STG(APTR(14, 1), ALDS(0, 1)),
               STG(BPTR(15, 0), BLDS(0, 0)), STG(BPTR(15, 1), BLDS(0, 1)), VMC(4));
    TILE(0, 2, STG(APTR(15, 0), ALDS(1, 0)), STG(APTR(15, 1), ALDS(1, 1)), , , VMC(0));
    TILE(1, 0, , , , , );

    // ---- fused epilogue: LDS transpose-reduce with per-row batch table ----
    float* q_lds = reinterpret_cast<float*>(pool);            // [16][256]
    float* sc_lds = reinterpret_cast<float*>(pool + 16384);   // [256]
    int* rowb = reinterpret_cast<int*>(pool + 17408);         // [256]
    float* red = reinterpret_cast<float*>(pool + 18432);      // [4][256][20]
    {
        int qb = tid >> 5;
        int kl = (tid & 31) * 8;
        const float4* src = reinterpret_cast<const float4*>(qv + (size_t)qb * HDIM + n0 + kl);
        float4 v0 = src[0], v1 = src[1];
        *reinterpret_cast<float4*>(&q_lds[qb * 256 + kl]) = v0;
        *reinterpret_cast<float4*>(&q_lds[qb * 256 + kl + 4]) = v1;
        if (tid < BN) sc_lds[tid] = score_w[n0 + tid];
        if (tid < BM) rowb[tid] = (m0 + tid < nkeep) ? (rowidx[m0 + tid] & 15) : 0;
    }
    __syncthreads();

#pragma unroll
    for (int mi = 0; mi < 8; ++mi) {
#pragma unroll
        for (int r = 0; r < 4; ++r) {
            int row = wr * 128 + mi * 16 + lh * 4 + r;
            int bq = rowb[row];
            float s = 0.f;
#pragma unroll
            for (int nj = 0; nj < 4; ++nj) {
                int kl = wc * 64 + nj * 16 + lq;
                float v = acc[mi][nj][r] + q_lds[bq * 256 + kl];
                float t = 1.f - 2.f / (__expf(2.f * v) + 1.f);  // tanh(v)
                s += sc_lds[kl] * t;
            }
            red[(wc * 256 + row) * 20 + lq] = s;
        }
    }
    __syncthreads();
    if (tid < BM) {
        float t = 0.f;
#pragma unroll
        for (int w4 = 0; w4 < 4; ++w4) {
            const f32x4* p = reinterpret_cast<const f32x4*>(&red[(w4 * 256 + tid) * 20]);
#pragma unroll
            for (int i = 0; i < 4; ++i) {
                f32x4 v = p[i];
                t += v[0] + v[1] + v[2] + v[3];
            }
        }
        part[(size_t)bn * M_TOT + m0 + tid] = t;
    }
#undef CLUSTER
#undef TILE
#undef RD8
#undef ALDS
#undef BLDS
}

// ---------------- kernel 2b: remainder rows [MMAIN, nkeep) — naive 32x256 MFMA tiles ----------
__global__ __launch_bounds__(256) void rem_kernel(const __hip_bfloat16* __restrict__ encb,
                                                  const __hip_bfloat16* __restrict__ web,
                                                  const float* __restrict__ qv,
                                                  const float* __restrict__ score_w,
                                                  const int* __restrict__ rowidx,
                                                  const int* __restrict__ nkp,
                                                  float* __restrict__ part) {
    int nkeep = nkp[0];
    int bid = blockIdx.x;
    int mt = bid >> 2, bn = bid & 3;
    int j0 = MMAIN + mt * 32;
    if (j0 >= nkeep) return;

    int tid = threadIdx.x, lane = tid & 63, w = tid >> 6;   // 4 waves
    int lq = lane & 15, lh = lane >> 4;
    int colblk = bn * 256 + w * 64;

    f32x4 acc[2][4];
#pragma unroll
    for (int i = 0; i < 2; i++)
#pragma unroll
        for (int j = 0; j < 4; j++) acc[i][j] = (f32x4)0.f;

    for (int kt = 0; kt < 32; ++kt) {
        int kb = kt * 32 + lh * 8;
        short8 a0 = *reinterpret_cast<const short8*>(encb + (size_t)(j0 + lq) * HDIM + kb);
        short8 a1 = *reinterpret_cast<const short8*>(encb + (size_t)(j0 + 16 + lq) * HDIM + kb);
#pragma unroll
        for (int nj = 0; nj < 4; ++nj) {
            short8 b = *reinterpret_cast<const short8*>(web + (size_t)(colblk + nj * 16 + lq) * HDIM + kb);
            acc[0][nj] = __builtin_amdgcn_mfma_f32_16x16x32_bf16(a0, b, acc[0][nj], 0, 0, 0);
            acc[1][nj] = __builtin_amdgcn_mfma_f32_16x16x32_bf16(a1, b, acc[1][nj], 0, 0, 0);
        }
    }

    __shared__ float eng[4][32];
#pragma unroll
    for (int mi = 0; mi < 2; ++mi) {
#pragma unroll
        for (int r = 0; r < 4; ++r) {
            int row = mi * 16 + lh * 4 + r;
            int j = j0 + row;
            int bq = (j < nkeep) ? (rowidx[j] & 15) : 0;
            float s = 0.f;
#pragma unroll
            for (int nj = 0; nj < 4; ++nj) {
                int kl = colblk + nj * 16 + lq;
                float v = acc[mi][nj][r] + qv[(size_t)bq * HDIM + kl];
                float t = 1.f - 2.f / (__expf(2.f * v) + 1.f);  // tanh(v)
                s += score_w[kl] * t;
            }
            for (int off = 1; off < 16; off <<= 1) s += __shfl_xor(s, off);
            if (lq == 0) eng[w][row] = s;
        }
    }
    __syncthreads();
    if (tid < 32) {
        float t = eng[0][tid] + eng[1][tid] + eng[2][tid] + eng[3][tid];
        part[(size_t)bn * M_TOT + j0 + tid] = t;
    }
}

// ---------------- kernel 3: gather partials via jof + mask + softmax over S ----------------
__global__ __launch_bounds__(256) void softmax_kernel(const float* __restrict__ part,
                                                      const int* __restrict__ mask,
                                                      const int* __restrict__ jof,
                                                      float* __restrict__ out) {
    int b = blockIdx.x;
    int tid = threadIdx.x;
    __shared__ float e_lds[SEQ];
    __shared__ float red[4], red2[4];
    int lane = tid & 63, wid = tid >> 6;
    float lmax = -3.4e38f;
    for (int it = 0; it < SEQ / 256; ++it) {
        int s = it * 256 + tid;
        float e = -1e12f;
        if (!mask[(size_t)b * SEQ + s]) {
            int m = s * BATCH + b;
            int j = jof[m];
            float acc = 0.f;
#pragma unroll
            for (int c = 0; c < NBLK; c++) acc += part[(size_t)c * M_TOT + j];
            e = acc;
        }
        e_lds[s] = e;
        lmax = fmaxf(lmax, e);
    }
    for (int off = 32; off; off >>= 1) lmax = fmaxf(lmax, __shfl_xor(lmax, off));
    if (lane == 0) red[wid] = lmax;
    __syncthreads();
    float gmax = fmaxf(fmaxf(red[0], red[1]), fmaxf(red[2], red[3]));
    float lsum = 0.f;
    for (int it = 0; it < SEQ / 256; ++it) {
        int s = it * 256 + tid;
        float p = __expf(e_lds[s] - gmax);
        e_lds[s] = p;
        lsum += p;
    }
    for (int off = 32; off; off >>= 1) lsum += __shfl_xor(lsum, off);
    if (lane == 0) red2[wid] = lsum;
    __syncthreads();
    float inv = 1.f / (red2[0] + red2[1] + red2[2] + red2[3]);
    for (int it = 0; it < SEQ / 256; ++it) {
        int s = it * 256 + tid;
        out[(size_t)b * SEQ + s] = e_lds[s] * inv;
    }
}

extern "C" void kernel_launch(void* const* d_in, const int* in_sizes, int n_in,
                              void* d_out, int out_size, void* d_ws, size_t ws_size,
                              hipStream_t stream) {
    const float* hidden   = (const float*)d_in[0];
    const float* enc      = (const float*)d_in[1];
    const int*   seq_mask = (const int*)d_in[2];
    const float* attn_w   = (const float*)d_in[3];
    const float* attn_b   = (const float*)d_in[4];
    const float* score_w  = (const float*)d_in[5];
    float* out = (float*)d_out;

    char* ws = (char*)d_ws;
    float* q = (float*)ws;                                            // 64 KB
    __hip_bfloat16* web = (__hip_bfloat16*)(ws + 65536);              // 2 MB
    float* part = (float*)(ws + 65536 + 2 * 1024 * 1024);             // 512 KB
    int* rowidx = (int*)(ws + 65536 + 2 * 1024 * 1024 + 512 * 1024);  // 128 KB
    int* jof    = (int*)(ws + 65536 + 2 * 1024 * 1024 + 640 * 1024);  // 128 KB
    int* nkeep  = (int*)(ws + 65536 + 2 * 1024 * 1024 + 768 * 1024);  // 4 B
    int* counts = (int*)(ws + 65536 + 2 * 1024 * 1024 + 772 * 1024);  // 512 B
    int* bases  = (int*)(ws + 65536 + 2 * 1024 * 1024 + 776 * 1024);  // 512 B
    __hip_bfloat16* encb = (__hip_bfloat16*)(ws + 65536 + 3 * 1024 * 1024);  // 64 MB

    scanA<<<dim3(128), dim3(256), 0, stream>>>(seq_mask, counts);
    scanB<<<dim3(1), dim3(64), 0, stream>>>(counts, bases, nkeep);
    scanC<<<dim3(128), dim3(256), 0, stream>>>(seq_mask, bases, rowidx, jof);
    prep_all<<<dim3(NB_ENC + NB_WE + NB_QK), dim3(256), 0, stream>>>(hidden, enc, attn_w, attn_b,
                                                                     rowidx, nkeep, q, web, encb);
    gemm8<<<dim3(256), dim3(512), 0, stream>>>(encb, web, q, score_w, rowidx, nkeep, part);
    rem_kernel<<<dim3(2048), dim3(256), 0, stream>>>(encb, web, q, score_w, rowidx, nkeep, part);
    softmax_kernel<<<dim3(BATCH), dim3(256), 0, stream>>>(part, seq_mask, jof, out);
}

// Round 22
// 110.868 us; speedup vs baseline: 1.1162x; 1.0286x over previous
//
#include <hip/hip_runtime.h>
#include <hip/hip_bf16.h>

#define HDIM 1024
#define SEQ 2048
#define BATCH 16
#define M_TOT (SEQ*BATCH)   // 32768
#define NBLK 4              // N split into 4 chunks of 256
#define BM 256
#define BN 256
#define BKT 64              // K-tile depth
#define NT (HDIM/BKT)       // 16 K-tiles
#define MMAIN 16384         // rows handled by the main 256-tile gemm (64 M-tiles)

// prep_all grid layout
#define NB_ENC ((M_TOT*HDIM)/(8*256))   // 16384
#define NB_WE  ((HDIM*HDIM)/(8*256))    // 512
#define NB_QK  (HDIM)                   // 1024

typedef __attribute__((ext_vector_type(8))) short short8;
typedef __attribute__((ext_vector_type(4))) float f32x4;

typedef const void __attribute__((address_space(1))) gvoid_t;
typedef void __attribute__((address_space(3))) svoid_t;
#define GLD16(gp, lp) __builtin_amdgcn_global_load_lds((gvoid_t*)(gp), (svoid_t*)(lp), 16, 0, 0)
#define VMC(N) asm volatile("s_waitcnt vmcnt(" #N ")" ::: "memory")

static __device__ __forceinline__ unsigned short f2bf(float f) {
    unsigned int x = __float_as_uint(f);
    unsigned int r = (x + 0x7FFFu + ((x >> 16) & 1u)) >> 16;  // RNE
    return (unsigned short)r;
}

// ---------------- compaction, parallel 2-phase (l-ascending order, same as R21) ----------------
// scanA: counts[c] = #kept in 512-int chunk c (64 blocks x 512 thr); also nkeep via last block?
// Keep it simple: counts only; scanC sums prefix itself and block 0 writes nkeep.
__global__ __launch_bounds__(512) void scanA(const int* __restrict__ mask,
                                             int* __restrict__ counts) {
    int idx = blockIdx.x * 512 + threadIdx.x;
    int flag = (mask[idx] == 0) ? 1 : 0;
    unsigned long long bal = __ballot(flag);
    __shared__ int wsum[8];
    int lane = threadIdx.x & 63, wv = threadIdx.x >> 6;
    if (lane == 0) wsum[wv] = __popcll(bal);
    __syncthreads();
    if (threadIdx.x == 0) {
        int s = 0;
#pragma unroll
        for (int w = 0; w < 8; ++w) s += wsum[w];
        counts[blockIdx.x] = s;
    }
}

// scanC: scatter rowidx/jof; each block derives its base from counts[0..bid); block 0 writes nkeep
__global__ __launch_bounds__(512) void scanC(const int* __restrict__ mask,
                                             const int* __restrict__ counts,
                                             int* __restrict__ rowidx,
                                             int* __restrict__ jof,
                                             int* __restrict__ nkeep) {
    __shared__ int bbase;
    __shared__ int wsum[8];
    int lane = threadIdx.x & 63, wv = threadIdx.x >> 6;
    if (threadIdx.x == 0) {
        int acc = 0;
        for (int c = 0; c < (int)blockIdx.x; ++c) acc += counts[c];
        bbase = acc;
        if (blockIdx.x == 0) {
            int tot = 0;
            for (int c = 0; c < 64; ++c) tot += counts[c];
            nkeep[0] = tot;
        }
    }
    int idx = blockIdx.x * 512 + threadIdx.x;
    int flag = (mask[idx] == 0) ? 1 : 0;
    unsigned long long bal = __ballot(flag);
    if (lane == 0) wsum[wv] = __popcll(bal);
    __syncthreads();
    int wbase = bbase;
    for (int w = 0; w < 8; ++w) if (w < wv) wbase += wsum[w];
    if (flag) {
        int excl = __popcll(bal & ((1ull << lane) - 1ull));
        int e = wbase + excl;
        int l = idx;
        int m = ((l & 2047) << 4) | (l >> 11);   // m = s*16 + b
        rowidx[e] = m;
        jof[m] = e;
    }
}

// ---------------- kernel 1: fused prep = compact-conv_enc + conv_we + qk ----------------
__global__ __launch_bounds__(256) void prep_all(const float* __restrict__ hidden,
                                                const float* __restrict__ enc,
                                                const float* __restrict__ attn_w,
                                                const float* __restrict__ attn_b,
                                                const int* __restrict__ rowidx,
                                                const int* __restrict__ nkp,
                                                float* __restrict__ q,
                                                __hip_bfloat16* __restrict__ web,
                                                __hip_bfloat16* __restrict__ encb) {
    int bid = blockIdx.x;
    if (bid < NB_ENC) {
        int nkeep = nkp[0];
        int npad = (nkeep + 255) & ~255;
        int plim = npad > MMAIN ? npad : MMAIN;    // main gemm always reads rows [0, MMAIN)
        int j = bid * 2 + (threadIdx.x >> 7);      // 2 rows per block
        if (j >= plim) return;
        int col = (threadIdx.x & 127) * 8;
        unsigned short* dst = (unsigned short*)encb + (size_t)j * HDIM + col;
        if (j >= nkeep) {
            short8 z = (short8)0;
            *reinterpret_cast<short8*>(dst) = z;
            return;
        }
        int m = rowidx[j];
        const float4* s4 = reinterpret_cast<const float4*>(enc + (size_t)m * HDIM + col);
        float4 a = s4[0], b = s4[1];
        union { unsigned short u[8]; short8 v; } cv;
        cv.u[0] = f2bf(a.x); cv.u[1] = f2bf(a.y); cv.u[2] = f2bf(a.z); cv.u[3] = f2bf(a.w);
        cv.u[4] = f2bf(b.x); cv.u[5] = f2bf(b.y); cv.u[6] = f2bf(b.z); cv.u[7] = f2bf(b.w);
        *reinterpret_cast<short8*>(dst) = cv.v;
        return;
    }
    if (bid < NB_ENC + NB_WE) {
        size_t i0 = ((size_t)(bid - NB_ENC) * 256 + threadIdx.x) * 8;
        int n = (int)(i0 >> 10);
        int h = (int)(i0 & 1023);
        const float4* src = reinterpret_cast<const float4*>(attn_w + (size_t)n * (2 * HDIM) + HDIM + h);
        float4 a = src[0], b = src[1];
        union { unsigned short u[8]; short8 v; } cv;
        cv.u[0] = f2bf(a.x); cv.u[1] = f2bf(a.y); cv.u[2] = f2bf(a.z); cv.u[3] = f2bf(a.w);
        cv.u[4] = f2bf(b.x); cv.u[5] = f2bf(b.y); cv.u[6] = f2bf(b.z); cv.u[7] = f2bf(b.w);
        *reinterpret_cast<short8*>((unsigned short*)web + i0) = cv.v;
        return;
    }
    int k = bid - (NB_ENC + NB_WE);
    int tid = threadIdx.x;
    const float* w = attn_w + (size_t)k * (2 * HDIM);
    float p[BATCH];
#pragma unroll
    for (int b = 0; b < BATCH; b++) p[b] = 0.f;
    for (int h = tid; h < HDIM; h += 256) {
        float wv = w[h];
#pragma unroll
        for (int b = 0; b < BATCH; b++) p[b] += hidden[b * HDIM + h] * wv;
    }
#pragma unroll
    for (int b = 0; b < BATCH; b++) {
        for (int off = 32; off; off >>= 1) p[b] += __shfl_down(p[b], off);
    }
    __shared__ float red[4][BATCH];
    int lane = tid & 63, wid = tid >> 6;
    if (lane == 0) {
#pragma unroll
        for (int b = 0; b < BATCH; b++) red[wid][b] = p[b];
    }
    __syncthreads();
    if (tid < BATCH) {
        float s = red[0][tid] + red[1][tid] + red[2][tid] + red[3][tid] + attn_b[k];
        q[(size_t)tid * HDIM + k] = s;
    }
}

// ---------------- kernel 2: 256x256 GEMM over rows [0, MMAIN), EXACTLY 256 tiles ----------------
__global__ __launch_bounds__(512, 2) void gemm8(const __hip_bfloat16* __restrict__ encb,
                                                const __hip_bfloat16* __restrict__ web,
                                                const float* __restrict__ qv,
                                                const float* __restrict__ score_w,
                                                const int* __restrict__ rowidx,
                                                const int* __restrict__ nkp,
                                                float* __restrict__ part) {
    __shared__ __align__(16) char pool[163840];

    int tid = threadIdx.x;
    int lane = tid & 63;
    int wid = tid >> 6;        // 0..7
    int wr = wid >> 2;         // 0..1  M half
    int wc = wid & 3;          // 0..3  N quarter

    // 256 blocks = 8 XCDs x 32; XCD x owns bm in [x*8, x*8+8), bn fastest
    int bid = blockIdx.x;
    int lin = (bid & 7) * 32 + (bid >> 3);
    int bm = lin >> 2;         // 0..63
    int bn = lin & 3;          // 0..3
    int m0 = bm * BM, n0 = bn * BN;

    int nkeep = nkp[0];

    int srow = tid >> 3;
    int scolb = (((tid & 7) ^ ((tid >> 3) & 7)) << 4);
    const char* eb = (const char*)encb;
    const char* wb = (const char*)web;

    auto STG = [&](const char* g, int ldsoff) {
        GLD16(g + (size_t)srow * 2048 + scolb, pool + ldsoff + wid * 1024);
        GLD16(g + (size_t)(srow + 64) * 2048 + scolb, pool + ldsoff + 8192 + wid * 1024);
    };
    auto APTR = [&](int kt, int h) { return eb + ((size_t)(m0 + h * 128) * HDIM + kt * BKT) * 2; };
    auto BPTR = [&](int kt, int h) { return wb + ((size_t)(n0 + h * 128) * HDIM + kt * BKT) * 2; };
#define ALDS(par, h) ((par) * 32768 + (h) * 16384)
#define BLDS(buf, h) (65536 + (buf) * 32768 + (h) * 16384)

    int lq = lane & 15, lh = lane >> 4;
    int flip = (lane & 7) << 4;
    int pks0 = lq * 128 + ((lh * 16) ^ flip);
    int pks1 = lq * 128 + (((64 + lh * 16)) ^ flip);
    int aFB = wr * 16384;
    int bOFF = (wc >> 1) * 16384 + (wc & 1) * 8192;

    f32x4 acc[8][4];
#pragma unroll
    for (int i = 0; i < 8; i++)
#pragma unroll
        for (int j = 0; j < 4; j++) acc[i][j] = (f32x4)0.f;
    short8 br[4][2];

#define RD8(off) (*reinterpret_cast<const short8*>(pool + (off)))

#define CLUSTER(Q, PAR, BB, STAGE_STMT)                                                   \
    {                                                                                     \
        if ((Q) == 0) {                                                                   \
            _Pragma("unroll") for (int nj = 0; nj < 4; ++nj) {                            \
                br[nj][0] = RD8(65536 + (BB) * 32768 + bOFF + nj * 2048 + pks0);          \
                br[nj][1] = RD8(65536 + (BB) * 32768 + bOFF + nj * 2048 + pks1);          \
            }                                                                             \
        }                                                                                 \
        short8 a0k0 = RD8(aFB + (PAR) * 32768 + (2 * (Q)) * 2048 + pks0);                 \
        short8 a0k1 = RD8(aFB + (PAR) * 32768 + (2 * (Q)) * 2048 + pks1);                 \
        short8 a1k0 = RD8(aFB + (PAR) * 32768 + (2 * (Q) + 1) * 2048 + pks0);             \
        short8 a1k1 = RD8(aFB + (PAR) * 32768 + (2 * (Q) + 1) * 2048 + pks1);             \
        STAGE_STMT;                                                                       \
        __builtin_amdgcn_s_setprio(1);                                                    \
        _Pragma("unroll") for (int nj = 0; nj < 4; ++nj) {                                \
            acc[2 * (Q)][nj] = __builtin_amdgcn_mfma_f32_16x16x32_bf16(a0k0, br[nj][0], acc[2 * (Q)][nj], 0, 0, 0); \
            acc[2 * (Q)][nj] = __builtin_amdgcn_mfma_f32_16x16x32_bf16(a0k1, br[nj][1], acc[2 * (Q)][nj], 0, 0, 0); \
            acc[2 * (Q) + 1][nj] = __builtin_amdgcn_mfma_f32_16x16x32_bf16(a1k0, br[nj][0], acc[2 * (Q) + 1][nj], 0, 0, 0); \
            acc[2 * (Q) + 1][nj] = __builtin_amdgcn_mfma_f32_16x16x32_bf16(a1k1, br[nj][1], acc[2 * (Q) + 1][nj], 0, 0, 0); \
        }                                                                                 \
        __builtin_amdgcn_s_setprio(0);                                                    \
    }

#define TILE(PAR, BB, S1, S2, S3, S4, CLOSE)                                              \
    {                                                                                     \
        CLUSTER(0, PAR, BB, S1);                                                          \
        CLUSTER(1, PAR, BB, S2);                                                          \
        CLUSTER(2, PAR, BB, S3);                                                          \
        CLUSTER(3, PAR, BB, S4);                                                          \
        CLOSE;                                                                            \
        __builtin_amdgcn_s_barrier();                                                     \
        __builtin_amdgcn_sched_barrier(0);                                                \
    }

    STG(APTR(0, 0), ALDS(0, 0));
    STG(APTR(0, 1), ALDS(0, 1));
    STG(BPTR(0, 0), BLDS(0, 0));
    STG(BPTR(0, 1), BLDS(0, 1));
    STG(BPTR(1, 0), BLDS(1, 0));
    STG(BPTR(1, 1), BLDS(1, 1));
    VMC(4);
    __builtin_amdgcn_s_barrier();
    __builtin_amdgcn_sched_barrier(0);

#pragma unroll 1
    for (int J = 0; J < 2; ++J) {
        int t = 6 * J;
        TILE(0, 0, STG(APTR(t + 1, 0), ALDS(1, 0)), STG(APTR(t + 1, 1), ALDS(1, 1)),
                   STG(BPTR(t + 2, 0), BLDS(2, 0)), STG(BPTR(t + 2, 1), BLDS(2, 1)), VMC(4));
        TILE(1, 1, STG(APTR(t + 2, 0), ALDS(0, 0)), STG(APTR(t + 2, 1), ALDS(0, 1)),
                   STG(BPTR(t + 3, 0), BLDS(0, 0)), STG(BPTR(t + 3, 1), BLDS(0, 1)), VMC(4));
        TILE(0, 2, STG(APTR(t + 3, 0), ALDS(1, 0)), STG(APTR(t + 3, 1), ALDS(1, 1)),
                   STG(BPTR(t + 4, 0), BLDS(1, 0)), STG(BPTR(t + 4, 1), BLDS(1, 1)), VMC(4));
        TILE(1, 0, STG(APTR(t + 4, 0), ALDS(0, 0)), STG(APTR(t + 4, 1), ALDS(0, 1)),
                   STG(BPTR(t + 5, 0), BLDS(2, 0)), STG(BPTR(t + 5, 1), BLDS(2, 1)), VMC(4));
        TILE(0, 1, STG(APTR(t + 5, 0), ALDS(1, 0)), STG(APTR(t + 5, 1), ALDS(1, 1)),
                   STG(BPTR(t + 6, 0), BLDS(0, 0)), STG(BPTR(t + 6, 1), BLDS(0, 1)), VMC(4));
        TILE(1, 2, STG(APTR(t + 6, 0), ALDS(0, 0)), STG(APTR(t + 6, 1), ALDS(0, 1)),
                   STG(BPTR(t + 7, 0), BLDS(1, 0)), STG(BPTR(t + 7, 1), BLDS(1, 1)), VMC(4));
    }
    TILE(0, 0, STG(APTR(13, 0), ALDS(1, 0)), STG(APTR(13, 1), ALDS(1, 1)),
               STG(BPTR(14, 0), BLDS(2, 0)), STG(BPTR(14, 1), BLDS(2, 1)), VMC(4));
    TILE(1, 1, STG(APTR(14, 0), ALDS(0, 0)), STG(APTR(14, 1), ALDS(0, 1)),
               STG(BPTR(15, 0), BLDS(0, 0)), STG(BPTR(15, 1), BLDS(0, 1)), VMC(4));
    TILE(0, 2, STG(APTR(15, 0), ALDS(1, 0)), STG(APTR(15, 1), ALDS(1, 1)), , , VMC(0));
    TILE(1, 0, , , , , );

    // ---- fused epilogue: LDS transpose-reduce with per-row batch table ----
    float* q_lds = reinterpret_cast<float*>(pool);            // [16][256]
    float* sc_lds = reinterpret_cast<float*>(pool + 16384);   // [256]
    int* rowb = reinterpret_cast<int*>(pool + 17408);         // [256]
    float* red = reinterpret_cast<float*>(pool + 18432);      // [4][256][20]
    {
        int qb = tid >> 5;
        int kl = (tid & 31) * 8;
        const float4* src = reinterpret_cast<const float4*>(qv + (size_t)qb * HDIM + n0 + kl);
        float4 v0 = src[0], v1 = src[1];
        *reinterpret_cast<float4*>(&q_lds[qb * 256 + kl]) = v0;
        *reinterpret_cast<float4*>(&q_lds[qb * 256 + kl + 4]) = v1;
        if (tid < BN) sc_lds[tid] = score_w[n0 + tid];
        if (tid < BM) rowb[tid] = (m0 + tid < nkeep) ? (rowidx[m0 + tid] & 15) : 0;
    }
    __syncthreads();

#pragma unroll
    for (int mi = 0; mi < 8; ++mi) {
#pragma unroll
        for (int r = 0; r < 4; ++r) {
            int row = wr * 128 + mi * 16 + lh * 4 + r;
            int bq = rowb[row];
            float s = 0.f;
#pragma unroll
            for (int nj = 0; nj < 4; ++nj) {
                int kl = wc * 64 + nj * 16 + lq;
                float v = acc[mi][nj][r] + q_lds[bq * 256 + kl];
                float t = 1.f - 2.f / (__expf(2.f * v) + 1.f);  // tanh(v)
                s += sc_lds[kl] * t;
            }
            red[(wc * 256 + row) * 20 + lq] = s;
        }
    }
    __syncthreads();
    if (tid < BM) {
        float t = 0.f;
#pragma unroll
        for (int w4 = 0; w4 < 4; ++w4) {
            const f32x4* p = reinterpret_cast<const f32x4*>(&red[(w4 * 256 + tid) * 20]);
#pragma unroll
            for (int i = 0; i < 4; ++i) {
                f32x4 v = p[i];
                t += v[0] + v[1] + v[2] + v[3];
            }
        }
        part[(size_t)bn * M_TOT + m0 + tid] = t;
    }
#undef CLUSTER
#undef TILE
#undef RD8
#undef ALDS
#undef BLDS
}

// ---------------- kernel 2b: remainder rows [MMAIN, nkeep) — naive 32x256 MFMA tiles ----------
__global__ __launch_bounds__(256) void rem_kernel(const __hip_bfloat16* __restrict__ encb,
                                                  const __hip_bfloat16* __restrict__ web,
                                                  const float* __restrict__ qv,
                                                  const float* __restrict__ score_w,
                                                  const int* __restrict__ rowidx,
                                                  const int* __restrict__ nkp,
                                                  float* __restrict__ part) {
    int nkeep = nkp[0];
    int bid = blockIdx.x;
    int mt = bid >> 2, bn = bid & 3;
    int j0 = MMAIN + mt * 32;
    if (j0 >= nkeep) return;

    int tid = threadIdx.x, lane = tid & 63, w = tid >> 6;   // 4 waves
    int lq = lane & 15, lh = lane >> 4;
    int colblk = bn * 256 + w * 64;

    f32x4 acc[2][4];
#pragma unroll
    for (int i = 0; i < 2; i++)
#pragma unroll
        for (int j = 0; j < 4; j++) acc[i][j] = (f32x4)0.f;

    for (int kt = 0; kt < 32; ++kt) {
        int kb = kt * 32 + lh * 8;
        short8 a0 = *reinterpret_cast<const short8*>(encb + (size_t)(j0 + lq) * HDIM + kb);
        short8 a1 = *reinterpret_cast<const short8*>(encb + (size_t)(j0 + 16 + lq) * HDIM + kb);
#pragma unroll
        for (int nj = 0; nj < 4; ++nj) {
            short8 b = *reinterpret_cast<const short8*>(web + (size_t)(colblk + nj * 16 + lq) * HDIM + kb);
            acc[0][nj] = __builtin_amdgcn_mfma_f32_16x16x32_bf16(a0, b, acc[0][nj], 0, 0, 0);
            acc[1][nj] = __builtin_amdgcn_mfma_f32_16x16x32_bf16(a1, b, acc[1][nj], 0, 0, 0);
        }
    }

    __shared__ float eng[4][32];
#pragma unroll
    for (int mi = 0; mi < 2; ++mi) {
#pragma unroll
        for (int r = 0; r < 4; ++r) {
            int row = mi * 16 + lh * 4 + r;
            int j = j0 + row;
            int bq = (j < nkeep) ? (rowidx[j] & 15) : 0;
            float s = 0.f;
#pragma unroll
            for (int nj = 0; nj < 4; ++nj) {
                int kl = colblk + nj * 16 + lq;
                float v = acc[mi][nj][r] + qv[(size_t)bq * HDIM + kl];
                float t = 1.f - 2.f / (__expf(2.f * v) + 1.f);  // tanh(v)
                s += score_w[kl] * t;
            }
            for (int off = 1; off < 16; off <<= 1) s += __shfl_xor(s, off);
            if (lq == 0) eng[w][row] = s;
        }
    }
    __syncthreads();
    if (tid < 32) {
        float t = eng[0][tid] + eng[1][tid] + eng[2][tid] + eng[3][tid];
        part[(size_t)bn * M_TOT + j0 + tid] = t;
    }
}

// ---------------- kernel 3: gather partials via jof + mask + softmax over S ----------------
__global__ __launch_bounds__(256) void softmax_kernel(const float* __restrict__ part,
                                                      const int* __restrict__ mask,
                                                      const int* __restrict__ jof,
                                                      float* __restrict__ out) {
    int b = blockIdx.x;
    int tid = threadIdx.x;
    __shared__ float e_lds[SEQ];
    __shared__ float red[4], red2[4];
    int lane = tid & 63, wid = tid >> 6;
    float lmax = -3.4e38f;
    for (int it = 0; it < SEQ / 256; ++it) {
        int s = it * 256 + tid;
        float e = -1e12f;
        if (!mask[(size_t)b * SEQ + s]) {
            int m = s * BATCH + b;
            int j = jof[m];
            float acc = 0.f;
#pragma unroll
            for (int c = 0; c < NBLK; c++) acc += part[(size_t)c * M_TOT + j];
            e = acc;
        }
        e_lds[s] = e;
        lmax = fmaxf(lmax, e);
    }
    for (int off = 32; off; off >>= 1) lmax = fmaxf(lmax, __shfl_xor(lmax, off));
    if (lane == 0) red[wid] = lmax;
    __syncthreads();
    float gmax = fmaxf(fmaxf(red[0], red[1]), fmaxf(red[2], red[3]));
    float lsum = 0.f;
    for (int it = 0; it < SEQ / 256; ++it) {
        int s = it * 256 + tid;
        float p = __expf(e_lds[s] - gmax);
        e_lds[s] = p;
        lsum += p;
    }
    for (int off = 32; off; off >>= 1) lsum += __shfl_xor(lsum, off);
    if (lane == 0) red2[wid] = lsum;
    __syncthreads();
    float inv = 1.f / (red2[0] + red2[1] + red2[2] + red2[3]);
    for (int it = 0; it < SEQ / 256; ++it) {
        int s = it * 256 + tid;
        out[(size_t)b * SEQ + s] = e_lds[s] * inv;
    }
}

extern "C" void kernel_launch(void* const* d_in, const int* in_sizes, int n_in,
                              void* d_out, int out_size, void* d_ws, size_t ws_size,
                              hipStream_t stream) {
    const float* hidden   = (const float*)d_in[0];
    const float* enc      = (const float*)d_in[1];
    const int*   seq_mask = (const int*)d_in[2];
    const float* attn_w   = (const float*)d_in[3];
    const float* attn_b   = (const float*)d_in[4];
    const float* score_w  = (const float*)d_in[5];
    float* out = (float*)d_out;

    char* ws = (char*)d_ws;
    float* q = (float*)ws;                                            // 64 KB
    __hip_bfloat16* web = (__hip_bfloat16*)(ws + 65536);              // 2 MB
    float* part = (float*)(ws + 65536 + 2 * 1024 * 1024);             // 512 KB
    int* rowidx = (int*)(ws + 65536 + 2 * 1024 * 1024 + 512 * 1024);  // 128 KB
    int* jof    = (int*)(ws + 65536 + 2 * 1024 * 1024 + 640 * 1024);  // 128 KB
    int* nkeep  = (int*)(ws + 65536 + 2 * 1024 * 1024 + 768 * 1024);  // 4 B
    int* counts = (int*)(ws + 65536 + 2 * 1024 * 1024 + 772 * 1024);  // 256 B
    __hip_bfloat16* encb = (__hip_bfloat16*)(ws + 65536 + 3 * 1024 * 1024);  // 64 MB

    scanA<<<dim3(64), dim3(512), 0, stream>>>(seq_mask, counts);
    scanC<<<dim3(64), dim3(512), 0, stream>>>(seq_mask, counts, rowidx, jof, nkeep);
    prep_all<<<dim3(NB_ENC + NB_WE + NB_QK), dim3(256), 0, stream>>>(hidden, enc, attn_w, attn_b,
                                                                     rowidx, nkeep, q, web, encb);
    gemm8<<<dim3(256), dim3(512), 0, stream>>>(encb, web, q, score_w, rowidx, nkeep, part);
    rem_kernel<<<dim3(2048), dim3(256), 0, stream>>>(encb, web, q, score_w, rowidx, nkeep, part);
    softmax_kernel<<<dim3(BATCH), dim3(256), 0, stream>>>(part, seq_mask, jof, out);
}